// Round 7
// baseline (732.707 us; speedup 1.0000x reference)
//
#include <hip/hip_runtime.h>
#include <stdint.h>

#define FH 64
#define FW 64
#define CIN 1536
#define C3C 512
#define C4C 1024
#define COUT 512
#define BATCH 16
#define NPIX 4096
#define NBOX 10
#define MPAD 256   // 10 boxes * 25 bins = 250, padded

typedef short v8s __attribute__((ext_vector_type(8)));
typedef float v4f __attribute__((ext_vector_type(4)));
typedef unsigned short u8s __attribute__((ext_vector_type(8)));

#define GLOAD_LDS16(g, l) __builtin_amdgcn_global_load_lds( \
    (const __attribute__((address_space(1))) void*)(g),     \
    (__attribute__((address_space(3))) void*)(l), 16, 0, 0)

__device__ __forceinline__ unsigned short f32_to_bf16(float f) {
    union { float f; uint32_t u; } v; v.f = f;
    uint32_t u = v.u;
    uint32_t r = (u + 0x7FFFu + ((u >> 16) & 1u)) >> 16;
    return (unsigned short)r;
}
__device__ __forceinline__ uint32_t pack_bf16(float a, float b) {
    return (uint32_t)f32_to_bf16(a) | ((uint32_t)f32_to_bf16(b) << 16);
}

// ---------------- BN constant folding -------------------------------------
__global__ void prep_bn(const float* __restrict__ bng, const float* __restrict__ bnb,
                        const float* __restrict__ bnm, const float* __restrict__ bnv,
                        const float* __restrict__ bconv,
                        float* __restrict__ scale, float* __restrict__ shift) {
    int o = threadIdx.x;
    if (o < COUT) {
        float inv = bng[o] / sqrtf(bnv[o] + 1e-5f);
        scale[o] = inv;
        shift[o] = bnb[o] + inv * (bconv[o] - bnm[o]);
    }
}

// ---------------- W f32 -> bf16 -------------------------------------------
__global__ void conv_w(const float* __restrict__ w, unsigned short* __restrict__ wbf, int n) {
    int i = blockIdx.x * 256 + threadIdx.x;
    if (i < n) wbf[i] = f32_to_bf16(w[i]);
}

// ---------------- build fusedT[b][pix][c] bf16 (K-major), v2 ---------------
// Tile: 128 channels x 64 pixels (one y row). bf16-pair u32 LDS transpose,
// stride 65 (write & read both conflict-free), uint4 global stores.
__global__ __launch_bounds__(256) void build_fusedT(const float* __restrict__ c3,
                                                    const float* __restrict__ c4,
                                                    unsigned short* __restrict__ fusedT) {
    __shared__ uint32_t lds[64 * 65];
    int ct = blockIdx.x;          // 0..11; <4 -> c3, else c4
    int y  = blockIdx.y;          // 0..63
    int b  = blockIdx.z;
    int t  = threadIdx.x;
    int pg  = t & 15;             // pixel quad (pix = pg*4..pg*4+3)
    int cpb = t >> 4;             // 0..15, cpair = cpb + r*16

    if (ct < 4) {
        int chbase = ct * 128;
        const float* src = c3 + ((size_t)(b * C3C + chbase) * FH + y) * FW + pg * 4;
        #pragma unroll
        for (int r = 0; r < 4; ++r) {
            int cp = cpb + r * 16;
            const float* s0 = src + (size_t)(2 * cp) * (FH * FW);
            float4 f0 = *(const float4*)s0;
            float4 f1 = *(const float4*)(s0 + FH * FW);
            uint32_t* L = lds + cp;
            L[(pg * 4 + 0) * 65] = pack_bf16(f0.x, f1.x);
            L[(pg * 4 + 1) * 65] = pack_bf16(f0.y, f1.y);
            L[(pg * 4 + 2) * 65] = pack_bf16(f0.z, f1.z);
            L[(pg * 4 + 3) * 65] = pack_bf16(f0.w, f1.w);
        }
    } else {
        int chbase = ct * 128 - 512;
        int jy = y >> 1;
        int jyB = min(max(jy + ((y & 1) ? 1 : -1), 0), 31);
        int k0 = 2 * pg;
        int km = max(k0 - 1, 0), kp = min(k0 + 2, 31);
        const float* base = c4 + (size_t)(b * C4C + chbase) * 1024;
        #pragma unroll
        for (int r = 0; r < 4; ++r) {
            int cp = cpb + r * 16;
            float v[2][4];
            #pragma unroll
            for (int h = 0; h < 2; ++h) {
                const float* pc = base + (size_t)(2 * cp + h) * 1024;
                const float* r0 = pc + jy * 32;
                const float* r1 = pc + jyB * 32;
                float rbm = 0.75f * r0[km]     + 0.25f * r1[km];
                float rb0 = 0.75f * r0[k0]     + 0.25f * r1[k0];
                float rb1 = 0.75f * r0[k0 + 1] + 0.25f * r1[k0 + 1];
                float rbp = 0.75f * r0[kp]     + 0.25f * r1[kp];
                v[h][0] = 0.75f * rb0 + 0.25f * rbm;   // x even: jxB = jx-1
                v[h][1] = 0.75f * rb0 + 0.25f * rb1;
                v[h][2] = 0.75f * rb1 + 0.25f * rb0;
                v[h][3] = 0.75f * rb1 + 0.25f * rbp;
            }
            uint32_t* L = lds + cp;
            #pragma unroll
            for (int j = 0; j < 4; ++j)
                L[(pg * 4 + j) * 65] = pack_bf16(v[0][j], v[1][j]);
        }
    }
    __syncthreads();
    // write phase: lanes = 16 channel-groups (contiguous 256 B) x 4 pixels/wave
    int cg  = t & 15;             // 8-channel group
    int pxb = t >> 4;             // pix = pxb + r*16
    int chout = ct * 128 + cg * 8;
    #pragma unroll
    for (int r = 0; r < 4; ++r) {
        int pix = pxb + r * 16;
        const uint32_t* L = lds + pix * 65 + cg * 4;
        uint4 w;
        w.x = L[0]; w.y = L[1]; w.z = L[2]; w.w = L[3];
        *(uint4*)(fusedT + ((size_t)b * NPIX + y * FW + pix) * CIN + chout) = w;
    }
}

// ---------------- GEMM + BN + ReLU, channel-major out, swizzled LDS --------
__global__ __launch_bounds__(256) void gemm_bn_relu(
        const unsigned short* __restrict__ wbf,
        const unsigned short* __restrict__ fusedT,
        const float* __restrict__ scale, const float* __restrict__ shift,
        unsigned short* __restrict__ attr) {
    __shared__ __align__(16) unsigned short lds_a[128 * 32];
    __shared__ __align__(16) unsigned short lds_b[128 * 32];
    int t  = threadIdx.x;
    int n0 = blockIdx.x * 128;
    int o0 = blockIdx.y * 128;
    int b  = blockIdx.z;
    int wave = t >> 6, lane = t & 63;
    int wm = wave & 1, wn = wave >> 1;
    int quad = lane >> 4, l16 = lane & 15;
    const unsigned short* fb = fusedT + (size_t)b * NPIX * CIN;

    v4f acc[4][4];
    #pragma unroll
    for (int i = 0; i < 4; ++i)
        #pragma unroll
        for (int j = 0; j < 4; ++j) acc[i][j] = (v4f)0.0f;

    int row = t >> 2;
    int colsw = (t & 3) ^ ((t >> 3) & 3);
    const unsigned short* ga0 = wbf + (size_t)(o0 + row) * CIN + colsw * 8;
    const unsigned short* ga1 = wbf + (size_t)(o0 + row + 64) * CIN + colsw * 8;
    const unsigned short* gb0 = fb + (size_t)(n0 + row) * CIN + colsw * 8;
    const unsigned short* gb1 = fb + (size_t)(n0 + row + 64) * CIN + colsw * 8;
    unsigned short* la0 = lds_a + wave * 512;
    unsigned short* la1 = lds_a + 2048 + wave * 512;
    unsigned short* lb0 = lds_b + wave * 512;
    unsigned short* lb1 = lds_b + 2048 + wave * 512;

    int csw = (l16 >> 1) & 3;

    for (int kt = 0; kt < CIN / 32; ++kt) {
        __syncthreads();
        GLOAD_LDS16(ga0, la0);
        GLOAD_LDS16(ga1, la1);
        GLOAD_LDS16(gb0, lb0);
        GLOAD_LDS16(gb1, lb1);
        ga0 += 32; ga1 += 32; gb0 += 32; gb1 += 32;
        __syncthreads();

        v8s wf[4], pf[4];
        #pragma unroll
        for (int i = 0; i < 4; ++i)
            wf[i] = *(const v8s*)(lds_a + (wm * 64 + i * 16 + l16) * 32 + (quad ^ csw) * 8);
        #pragma unroll
        for (int j = 0; j < 4; ++j)
            pf[j] = *(const v8s*)(lds_b + (wn * 64 + j * 16 + l16) * 32 + (quad ^ csw) * 8);
        #pragma unroll
        for (int i = 0; i < 4; ++i)
            #pragma unroll
            for (int j = 0; j < 4; ++j)
                acc[i][j] = __builtin_amdgcn_mfma_f32_16x16x32_bf16(wf[i], pf[j], acc[i][j], 0, 0, 0);
    }

    unsigned short* ab = attr + (size_t)b * COUT * NPIX;
    #pragma unroll
    for (int i = 0; i < 4; ++i) {
        int obase = o0 + wm * 64 + i * 16 + quad * 4;
        #pragma unroll
        for (int r = 0; r < 4; ++r) {
            int oo = obase + r;
            float sc = scale[oo], sh = shift[oo];
            #pragma unroll
            for (int j = 0; j < 4; ++j) {
                int n = n0 + wn * 64 + j * 16 + l16;
                float v = acc[i][j][r] * sc + sh;
                v = fmaxf(v, 0.0f);
                ab[(size_t)oo * NPIX + n] = f32_to_bf16(v);
            }
        }
    }
}

// ---------------- build pooling matrix P[b][m][pix] bf16 -------------------
__global__ __launch_bounds__(256) void build_P(const float* __restrict__ boxes,
                                               unsigned short* __restrict__ P) {
    int br = blockIdx.x;                 // 0..159
    int b  = br / NBOX;
    int mb = (br % NBOX) * 25;
    int t  = threadIdx.x;
    int y  = t >> 2;                     // 0..63
    int x0 = (t & 3) * 16;
    const float* bx = boxes + (size_t)br * 4;
    int x1 = min(max((int)floorf(bx[0] * 0.125f), 0), 63);
    int y1 = min(max((int)floorf(bx[1] * 0.125f), 0), 63);
    int x2 = min(max((int)ceilf (bx[2] * 0.125f), 0), 63);
    int y2 = min(max((int)ceilf (bx[3] * 0.125f), 0), 63);
    if (x2 <= x1) x2 = min(x1 + 1, 64);
    if (y2 <= y1) y2 = min(y1 + 1, 64);
    int Lx = x2 - x1, Ly = y2 - y1;
    float wy[5];
    float vx[5][16];
    #pragma unroll
    for (int k = 0; k < 5; ++k) {
        int sx = x1 + (k * Lx) / 5;
        int ex = x1 + ((k + 1) * Lx + 4) / 5;
        int sy = y1 + (k * Ly) / 5;
        int ey = y1 + ((k + 1) * Ly + 4) / 5;
        wy[k] = (y >= sy && y < ey) ? 1.0f / (float)(ey - sy) : 0.0f;
        float ix = 1.0f / (float)(ex - sx);
        #pragma unroll
        for (int i = 0; i < 16; ++i) {
            int xi = x0 + i;
            vx[k][i] = (xi >= sx && xi < ex) ? ix : 0.0f;
        }
    }
    unsigned short* base = P + (size_t)b * MPAD * NPIX + y * FW + x0;
    #pragma unroll
    for (int p = 0; p < 5; ++p)
        #pragma unroll
        for (int q = 0; q < 5; ++q) {
            u8s o0v, o1v;
            #pragma unroll
            for (int i = 0; i < 8; ++i) {
                o0v[i] = f32_to_bf16(wy[p] * vx[q][i]);
                o1v[i] = f32_to_bf16(wy[p] * vx[q][8 + i]);
            }
            unsigned short* dst = base + (size_t)(mb + p * 5 + q) * NPIX;
            *(u8s*)(dst)     = o0v;
            *(u8s*)(dst + 8) = o1v;
        }
}

// ---------------- pool GEMM, K-split x4, atomic accumulate -----------------
// out[br][c][bin] += P[m, kseg] . attr[c, kseg]
__global__ __launch_bounds__(256) void pool_gemm(
        const unsigned short* __restrict__ P,
        const unsigned short* __restrict__ attr,
        float* __restrict__ out) {
    __shared__ __align__(16) unsigned short lds_a[128 * 32];
    __shared__ __align__(16) unsigned short lds_b[128 * 32];
    int t  = threadIdx.x;
    int m0 = blockIdx.x * 128;           // bin-row tile (0 or 128)
    int c0 = (blockIdx.y & 3) * 128;     // channel tile
    int seg = blockIdx.y >> 2;           // K segment (0..3), 1024 pix each
    int b  = blockIdx.z;
    int wave = t >> 6, lane = t & 63;
    int wm = wave & 1, wn = wave >> 1;
    int quad = lane >> 4, l16 = lane & 15;
    const unsigned short* Pb = P + (size_t)b * MPAD * NPIX + seg * 1024;
    const unsigned short* ab = attr + (size_t)b * COUT * NPIX + seg * 1024;

    v4f acc[4][4];
    #pragma unroll
    for (int i = 0; i < 4; ++i)
        #pragma unroll
        for (int j = 0; j < 4; ++j) acc[i][j] = (v4f)0.0f;

    int row = t >> 2;
    int colsw = (t & 3) ^ ((t >> 3) & 3);
    const unsigned short* ga0 = Pb + (size_t)(m0 + row) * NPIX + colsw * 8;
    const unsigned short* ga1 = Pb + (size_t)(m0 + row + 64) * NPIX + colsw * 8;
    const unsigned short* gb0 = ab + (size_t)(c0 + row) * NPIX + colsw * 8;
    const unsigned short* gb1 = ab + (size_t)(c0 + row + 64) * NPIX + colsw * 8;
    unsigned short* la0 = lds_a + wave * 512;
    unsigned short* la1 = lds_a + 2048 + wave * 512;
    unsigned short* lb0 = lds_b + wave * 512;
    unsigned short* lb1 = lds_b + 2048 + wave * 512;

    int csw = (l16 >> 1) & 3;

    for (int kt = 0; kt < 1024 / 32; ++kt) {
        __syncthreads();
        GLOAD_LDS16(ga0, la0);
        GLOAD_LDS16(ga1, la1);
        GLOAD_LDS16(gb0, lb0);
        GLOAD_LDS16(gb1, lb1);
        ga0 += 32; ga1 += 32; gb0 += 32; gb1 += 32;
        __syncthreads();

        v8s pA[4], pB[4];
        #pragma unroll
        for (int i = 0; i < 4; ++i)
            pA[i] = *(const v8s*)(lds_a + (wm * 64 + i * 16 + l16) * 32 + (quad ^ csw) * 8);
        #pragma unroll
        for (int j = 0; j < 4; ++j)
            pB[j] = *(const v8s*)(lds_b + (wn * 64 + j * 16 + l16) * 32 + (quad ^ csw) * 8);
        #pragma unroll
        for (int i = 0; i < 4; ++i)
            #pragma unroll
            for (int j = 0; j < 4; ++j)
                acc[i][j] = __builtin_amdgcn_mfma_f32_16x16x32_bf16(pA[i], pB[j], acc[i][j], 0, 0, 0);
    }

    #pragma unroll
    for (int i = 0; i < 4; ++i) {
        #pragma unroll
        for (int r = 0; r < 4; ++r) {
            int mrow = m0 + wm * 64 + i * 16 + quad * 4 + r;
            if (mrow < 250) {
                int box = mrow / 25;
                int bin = mrow - box * 25;
                size_t base = 640 + (size_t)(b * NBOX + box) * (COUT * 25) + bin;
                #pragma unroll
                for (int j = 0; j < 4; ++j) {
                    int c = c0 + wn * 64 + j * 16 + l16;
                    unsafeAtomicAdd(&out[base + (size_t)c * 25], acc[i][j][r]);
                }
            }
        }
    }
}

extern "C" void kernel_launch(void* const* d_in, const int* in_sizes, int n_in,
                              void* d_out, int out_size, void* d_ws, size_t ws_size,
                              hipStream_t stream) {
    const float* c3     = (const float*)d_in[0];
    const float* c4     = (const float*)d_in[1];
    const float* boxes  = (const float*)d_in[2];
    const float* w_conv = (const float*)d_in[3];
    const float* b_conv = (const float*)d_in[4];
    const float* bng    = (const float*)d_in[5];
    const float* bnb    = (const float*)d_in[6];
    const float* bnm    = (const float*)d_in[7];
    const float* bnv    = (const float*)d_in[8];
    float* out = (float*)d_out;

    char* ws = (char*)d_ws;
    // layout: fusedT bf16 [16][4096][1536] | wbf | scale | shift | attr bf16 [16][512][4096]
    // P bf16 [16][256][4096] (33.5 MB) ALIASES fusedT (dead after gemm; stream-ordered).
    unsigned short* fusedT = (unsigned short*)ws;                       // 201326592 B
    unsigned short* P      = (unsigned short*)ws;                       //  33554432 B (alias)
    unsigned short* wbf    = (unsigned short*)(ws + 201326592);         //   1572864 B
    float* scale           = (float*)(ws + 202899456);                  //      2048 B
    float* shift           = (float*)(ws + 202901504);                  //      2048 B
    unsigned short* attr   = (unsigned short*)(ws + 202903552);         //  67108864 B

    hipMemsetAsync(d_out, 0, (size_t)out_size * sizeof(float), stream);
    hipMemcpyAsync(d_out, d_in[2], 640 * sizeof(float), hipMemcpyDeviceToDevice, stream);
    prep_bn<<<1, 512, 0, stream>>>(bng, bnb, bnm, bnv, b_conv, scale, shift);
    conv_w<<<(COUT * CIN + 255) / 256, 256, 0, stream>>>(w_conv, wbf, COUT * CIN);
    build_fusedT<<<dim3(12, 64, 16), 256, 0, stream>>>(c3, c4, fusedT);
    gemm_bn_relu<<<dim3(32, 4, 16), 256, 0, stream>>>(wbf, fusedT, scale, shift, attr);
    build_P<<<160, 256, 0, stream>>>(boxes, P);
    pool_gemm<<<dim3(2, 16, 16), 256, 0, stream>>>(P, attr, out);
    (void)in_sizes; (void)n_in; (void)out_size; (void)ws_size;
}

// Round 8
// 547.037 us; speedup vs baseline: 1.3394x; 1.3394x over previous
//
#include <hip/hip_runtime.h>
#include <stdint.h>

#define FH 64
#define FW 64
#define CIN 1536
#define C3C 512
#define C4C 1024
#define COUT 512
#define BATCH 16
#define NPIX 4096
#define NBOX 10
#define MPAD 256   // 10 boxes * 25 bins = 250, padded

typedef short v8s __attribute__((ext_vector_type(8)));
typedef float v4f __attribute__((ext_vector_type(4)));
typedef unsigned short u8s __attribute__((ext_vector_type(8)));

#define GLOAD_LDS16(g, l) __builtin_amdgcn_global_load_lds( \
    (const __attribute__((address_space(1))) void*)(g),     \
    (__attribute__((address_space(3))) void*)(l), 16, 0, 0)

__device__ __forceinline__ unsigned short f32_to_bf16(float f) {
    union { float f; uint32_t u; } v; v.f = f;
    uint32_t u = v.u;
    uint32_t r = (u + 0x7FFFu + ((u >> 16) & 1u)) >> 16;
    return (unsigned short)r;
}
__device__ __forceinline__ uint32_t pack_bf16(float a, float b) {
    return (uint32_t)f32_to_bf16(a) | ((uint32_t)f32_to_bf16(b) << 16);
}

// ---------------- BN constant folding -------------------------------------
__global__ void prep_bn(const float* __restrict__ bng, const float* __restrict__ bnb,
                        const float* __restrict__ bnm, const float* __restrict__ bnv,
                        const float* __restrict__ bconv,
                        float* __restrict__ scale, float* __restrict__ shift) {
    int o = threadIdx.x;
    if (o < COUT) {
        float inv = bng[o] / sqrtf(bnv[o] + 1e-5f);
        scale[o] = inv;
        shift[o] = bnb[o] + inv * (bconv[o] - bnm[o]);
    }
}

// ---------------- W f32 -> bf16 -------------------------------------------
__global__ void conv_w(const float* __restrict__ w, unsigned short* __restrict__ wbf, int n) {
    int i = blockIdx.x * 256 + threadIdx.x;
    if (i < n) wbf[i] = f32_to_bf16(w[i]);
}

// ---------------- build fusedT[b][pix][c] bf16 (K-major), v2 ---------------
__global__ __launch_bounds__(256) void build_fusedT(const float* __restrict__ c3,
                                                    const float* __restrict__ c4,
                                                    unsigned short* __restrict__ fusedT) {
    __shared__ uint32_t lds[64 * 65];
    int ct = blockIdx.x;          // 0..11; <4 -> c3, else c4
    int y  = blockIdx.y;          // 0..63
    int b  = blockIdx.z;
    int t  = threadIdx.x;
    int pg  = t & 15;             // pixel quad (pix = pg*4..pg*4+3)
    int cpb = t >> 4;             // 0..15, cpair = cpb + r*16

    if (ct < 4) {
        int chbase = ct * 128;
        const float* src = c3 + ((size_t)(b * C3C + chbase) * FH + y) * FW + pg * 4;
        #pragma unroll
        for (int r = 0; r < 4; ++r) {
            int cp = cpb + r * 16;
            const float* s0 = src + (size_t)(2 * cp) * (FH * FW);
            float4 f0 = *(const float4*)s0;
            float4 f1 = *(const float4*)(s0 + FH * FW);
            uint32_t* L = lds + cp;
            L[(pg * 4 + 0) * 65] = pack_bf16(f0.x, f1.x);
            L[(pg * 4 + 1) * 65] = pack_bf16(f0.y, f1.y);
            L[(pg * 4 + 2) * 65] = pack_bf16(f0.z, f1.z);
            L[(pg * 4 + 3) * 65] = pack_bf16(f0.w, f1.w);
        }
    } else {
        int chbase = ct * 128 - 512;
        int jy = y >> 1;
        int jyB = min(max(jy + ((y & 1) ? 1 : -1), 0), 31);
        int k0 = 2 * pg;
        int km = max(k0 - 1, 0), kp = min(k0 + 2, 31);
        const float* base = c4 + (size_t)(b * C4C + chbase) * 1024;
        #pragma unroll
        for (int r = 0; r < 4; ++r) {
            int cp = cpb + r * 16;
            float v[2][4];
            #pragma unroll
            for (int h = 0; h < 2; ++h) {
                const float* pc = base + (size_t)(2 * cp + h) * 1024;
                const float* r0 = pc + jy * 32;
                const float* r1 = pc + jyB * 32;
                float rbm = 0.75f * r0[km]     + 0.25f * r1[km];
                float rb0 = 0.75f * r0[k0]     + 0.25f * r1[k0];
                float rb1 = 0.75f * r0[k0 + 1] + 0.25f * r1[k0 + 1];
                float rbp = 0.75f * r0[kp]     + 0.25f * r1[kp];
                v[h][0] = 0.75f * rb0 + 0.25f * rbm;   // x even: jxB = jx-1
                v[h][1] = 0.75f * rb0 + 0.25f * rb1;
                v[h][2] = 0.75f * rb1 + 0.25f * rb0;
                v[h][3] = 0.75f * rb1 + 0.25f * rbp;
            }
            uint32_t* L = lds + cp;
            #pragma unroll
            for (int j = 0; j < 4; ++j)
                L[(pg * 4 + j) * 65] = pack_bf16(v[0][j], v[1][j]);
        }
    }
    __syncthreads();
    int cg  = t & 15;             // 8-channel group
    int pxb = t >> 4;             // pix = pxb + r*16
    int chout = ct * 128 + cg * 8;
    #pragma unroll
    for (int r = 0; r < 4; ++r) {
        int pix = pxb + r * 16;
        const uint32_t* L = lds + pix * 65 + cg * 4;
        uint4 w;
        w.x = L[0]; w.y = L[1]; w.z = L[2]; w.w = L[3];
        *(uint4*)(fusedT + ((size_t)b * NPIX + y * FW + pix) * CIN + chout) = w;
    }
}

// ---------------- GEMM + BN + ReLU, channel-major out, swizzled LDS --------
__global__ __launch_bounds__(256) void gemm_bn_relu(
        const unsigned short* __restrict__ wbf,
        const unsigned short* __restrict__ fusedT,
        const float* __restrict__ scale, const float* __restrict__ shift,
        unsigned short* __restrict__ attr) {
    __shared__ __align__(16) unsigned short lds_a[128 * 32];
    __shared__ __align__(16) unsigned short lds_b[128 * 32];
    int t  = threadIdx.x;
    int n0 = blockIdx.x * 128;
    int o0 = blockIdx.y * 128;
    int b  = blockIdx.z;
    int wave = t >> 6, lane = t & 63;
    int wm = wave & 1, wn = wave >> 1;
    int quad = lane >> 4, l16 = lane & 15;
    const unsigned short* fb = fusedT + (size_t)b * NPIX * CIN;

    v4f acc[4][4];
    #pragma unroll
    for (int i = 0; i < 4; ++i)
        #pragma unroll
        for (int j = 0; j < 4; ++j) acc[i][j] = (v4f)0.0f;

    int row = t >> 2;
    int colsw = (t & 3) ^ ((t >> 3) & 3);
    const unsigned short* ga0 = wbf + (size_t)(o0 + row) * CIN + colsw * 8;
    const unsigned short* ga1 = wbf + (size_t)(o0 + row + 64) * CIN + colsw * 8;
    const unsigned short* gb0 = fb + (size_t)(n0 + row) * CIN + colsw * 8;
    const unsigned short* gb1 = fb + (size_t)(n0 + row + 64) * CIN + colsw * 8;
    unsigned short* la0 = lds_a + wave * 512;
    unsigned short* la1 = lds_a + 2048 + wave * 512;
    unsigned short* lb0 = lds_b + wave * 512;
    unsigned short* lb1 = lds_b + 2048 + wave * 512;

    int csw = (l16 >> 1) & 3;

    for (int kt = 0; kt < CIN / 32; ++kt) {
        __syncthreads();
        GLOAD_LDS16(ga0, la0);
        GLOAD_LDS16(ga1, la1);
        GLOAD_LDS16(gb0, lb0);
        GLOAD_LDS16(gb1, lb1);
        ga0 += 32; ga1 += 32; gb0 += 32; gb1 += 32;
        __syncthreads();

        v8s wf[4], pf[4];
        #pragma unroll
        for (int i = 0; i < 4; ++i)
            wf[i] = *(const v8s*)(lds_a + (wm * 64 + i * 16 + l16) * 32 + (quad ^ csw) * 8);
        #pragma unroll
        for (int j = 0; j < 4; ++j)
            pf[j] = *(const v8s*)(lds_b + (wn * 64 + j * 16 + l16) * 32 + (quad ^ csw) * 8);
        #pragma unroll
        for (int i = 0; i < 4; ++i)
            #pragma unroll
            for (int j = 0; j < 4; ++j)
                acc[i][j] = __builtin_amdgcn_mfma_f32_16x16x32_bf16(wf[i], pf[j], acc[i][j], 0, 0, 0);
    }

    unsigned short* ab = attr + (size_t)b * COUT * NPIX;
    #pragma unroll
    for (int i = 0; i < 4; ++i) {
        int obase = o0 + wm * 64 + i * 16 + quad * 4;
        #pragma unroll
        for (int r = 0; r < 4; ++r) {
            int oo = obase + r;
            float sc = scale[oo], sh = shift[oo];
            #pragma unroll
            for (int j = 0; j < 4; ++j) {
                int n = n0 + wn * 64 + j * 16 + l16;
                float v = acc[i][j][r] * sc + sh;
                v = fmaxf(v, 0.0f);
                ab[(size_t)oo * NPIX + n] = f32_to_bf16(v);
            }
        }
    }
}

// ---------------- build pooling matrix P[b][m][pix] bf16, v2 ---------------
// one block per (box, bin m25); each thread writes 32 contiguous bytes.
__global__ __launch_bounds__(256) void build_P(const float* __restrict__ boxes,
                                               unsigned short* __restrict__ P) {
    int br  = blockIdx.x;                // 0..159
    int m25 = blockIdx.y;                // 0..24
    int b   = br / NBOX;
    int m   = (br % NBOX) * 25 + m25;
    int p   = m25 / 5, q = m25 % 5;
    int t   = threadIdx.x;
    int y   = t >> 2;                    // 0..63
    int x0  = (t & 3) * 16;
    const float* bx = boxes + (size_t)br * 4;
    int x1 = min(max((int)floorf(bx[0] * 0.125f), 0), 63);
    int y1 = min(max((int)floorf(bx[1] * 0.125f), 0), 63);
    int x2 = min(max((int)ceilf (bx[2] * 0.125f), 0), 63);
    int y2 = min(max((int)ceilf (bx[3] * 0.125f), 0), 63);
    if (x2 <= x1) x2 = min(x1 + 1, 64);
    if (y2 <= y1) y2 = min(y1 + 1, 64);
    int Lx = x2 - x1, Ly = y2 - y1;
    int sx = x1 + (q * Lx) / 5;
    int ex = x1 + ((q + 1) * Lx + 4) / 5;
    int sy = y1 + (p * Ly) / 5;
    int ey = y1 + ((p + 1) * Ly + 4) / 5;
    float wyv = (y >= sy && y < ey) ? 1.0f / (float)(ey - sy) : 0.0f;
    float ix  = wyv / (float)(ex - sx);
    u8s o0v, o1v;
    #pragma unroll
    for (int i = 0; i < 8; ++i) {
        int xa = x0 + i, xb = x0 + 8 + i;
        o0v[i] = f32_to_bf16((xa >= sx && xa < ex) ? ix : 0.0f);
        o1v[i] = f32_to_bf16((xb >= sx && xb < ex) ? ix : 0.0f);
    }
    unsigned short* dst = P + ((size_t)b * MPAD + m) * NPIX + y * FW + x0;
    *(u8s*)(dst)     = o0v;
    *(u8s*)(dst + 8) = o1v;
}

// ---------------- pool GEMM, K-split x4, dense partials --------------------
// part2[seg][b][m][c] = P[m, kseg] . attr[c, kseg]
__global__ __launch_bounds__(256) void pool_gemm(
        const unsigned short* __restrict__ P,
        const unsigned short* __restrict__ attr,
        float* __restrict__ part2) {
    __shared__ __align__(16) unsigned short lds_a[128 * 32];
    __shared__ __align__(16) unsigned short lds_b[128 * 32];
    int t  = threadIdx.x;
    int m0 = blockIdx.x * 128;           // bin-row tile (0 or 128)
    int c0 = (blockIdx.y & 3) * 128;     // channel tile
    int seg = blockIdx.y >> 2;           // K segment (0..3), 1024 pix each
    int b  = blockIdx.z;
    int wave = t >> 6, lane = t & 63;
    int wm = wave & 1, wn = wave >> 1;
    int quad = lane >> 4, l16 = lane & 15;
    const unsigned short* Pb = P + (size_t)b * MPAD * NPIX + seg * 1024;
    const unsigned short* ab = attr + (size_t)b * COUT * NPIX + seg * 1024;

    v4f acc[4][4];
    #pragma unroll
    for (int i = 0; i < 4; ++i)
        #pragma unroll
        for (int j = 0; j < 4; ++j) acc[i][j] = (v4f)0.0f;

    int row = t >> 2;
    int colsw = (t & 3) ^ ((t >> 3) & 3);
    const unsigned short* ga0 = Pb + (size_t)(m0 + row) * NPIX + colsw * 8;
    const unsigned short* ga1 = Pb + (size_t)(m0 + row + 64) * NPIX + colsw * 8;
    const unsigned short* gb0 = ab + (size_t)(c0 + row) * NPIX + colsw * 8;
    const unsigned short* gb1 = ab + (size_t)(c0 + row + 64) * NPIX + colsw * 8;
    unsigned short* la0 = lds_a + wave * 512;
    unsigned short* la1 = lds_a + 2048 + wave * 512;
    unsigned short* lb0 = lds_b + wave * 512;
    unsigned short* lb1 = lds_b + 2048 + wave * 512;

    int csw = (l16 >> 1) & 3;

    for (int kt = 0; kt < 1024 / 32; ++kt) {
        __syncthreads();
        GLOAD_LDS16(ga0, la0);
        GLOAD_LDS16(ga1, la1);
        GLOAD_LDS16(gb0, lb0);
        GLOAD_LDS16(gb1, lb1);
        ga0 += 32; ga1 += 32; gb0 += 32; gb1 += 32;
        __syncthreads();

        v8s pA[4], pB[4];
        #pragma unroll
        for (int i = 0; i < 4; ++i)
            pA[i] = *(const v8s*)(lds_a + (wm * 64 + i * 16 + l16) * 32 + (quad ^ csw) * 8);
        #pragma unroll
        for (int j = 0; j < 4; ++j)
            pB[j] = *(const v8s*)(lds_b + (wn * 64 + j * 16 + l16) * 32 + (quad ^ csw) * 8);
        #pragma unroll
        for (int i = 0; i < 4; ++i)
            #pragma unroll
            for (int j = 0; j < 4; ++j)
                acc[i][j] = __builtin_amdgcn_mfma_f32_16x16x32_bf16(pA[i], pB[j], acc[i][j], 0, 0, 0);
    }

    // dense coalesced partial store: part2[seg][b][m][c]
    float* pp = part2 + (((size_t)seg * BATCH + b) * MPAD) * COUT;
    #pragma unroll
    for (int i = 0; i < 4; ++i) {
        #pragma unroll
        for (int r = 0; r < 4; ++r) {
            int mrow = m0 + wm * 64 + i * 16 + quad * 4 + r;
            #pragma unroll
            for (int j = 0; j < 4; ++j) {
                int c = c0 + wn * 64 + j * 16 + l16;
                pp[(size_t)mrow * COUT + c] = acc[i][j][r];
            }
        }
    }
}

// ---------------- reduce 4 segs, transpose into d_out ----------------------
__global__ __launch_bounds__(256) void pool_reduce(const float* __restrict__ part2,
                                                   float* __restrict__ out) {
    const size_t SEG = (size_t)BATCH * MPAD * COUT;
    int i = blockIdx.x * 256 + threadIdx.x;      // over 16*256*512
    int c = i & (COUT - 1);
    int m = (i >> 9) & (MPAD - 1);
    int b = i >> 17;
    if (m >= 250) return;
    float s = part2[i] + part2[i + SEG] + part2[i + 2 * SEG] + part2[i + 3 * SEG];
    int box = m / 25, bin = m - box * 25;
    out[640 + ((size_t)(b * NBOX + box) * COUT + c) * 25 + bin] = s;
}

extern "C" void kernel_launch(void* const* d_in, const int* in_sizes, int n_in,
                              void* d_out, int out_size, void* d_ws, size_t ws_size,
                              hipStream_t stream) {
    const float* c3     = (const float*)d_in[0];
    const float* c4     = (const float*)d_in[1];
    const float* boxes  = (const float*)d_in[2];
    const float* w_conv = (const float*)d_in[3];
    const float* b_conv = (const float*)d_in[4];
    const float* bng    = (const float*)d_in[5];
    const float* bnb    = (const float*)d_in[6];
    const float* bnm    = (const float*)d_in[7];
    const float* bnv    = (const float*)d_in[8];
    float* out = (float*)d_out;

    char* ws = (char*)d_ws;
    // layout: fusedT bf16 [16][4096][1536] | wbf | scale | shift | attr bf16 [16][512][4096]
    // P bf16 [16][256][4096] (33.5 MB) and part2 f32 [4][16][256][512] (33.5 MB)
    // both ALIAS the fusedT region (dead after gemm; stream-ordered).
    unsigned short* fusedT = (unsigned short*)ws;                       // 201326592 B
    unsigned short* P      = (unsigned short*)ws;                       //  33554432 B (alias)
    float* part2           = (float*)(ws + 33554432);                   //  33554432 B (alias)
    unsigned short* wbf    = (unsigned short*)(ws + 201326592);         //   1572864 B
    float* scale           = (float*)(ws + 202899456);                  //      2048 B
    float* shift           = (float*)(ws + 202901504);                  //      2048 B
    unsigned short* attr   = (unsigned short*)(ws + 202903552);         //  67108864 B

    hipMemcpyAsync(d_out, d_in[2], 640 * sizeof(float), hipMemcpyDeviceToDevice, stream);
    prep_bn<<<1, 512, 0, stream>>>(bng, bnb, bnm, bnv, b_conv, scale, shift);
    conv_w<<<(COUT * CIN + 255) / 256, 256, 0, stream>>>(w_conv, wbf, COUT * CIN);
    build_fusedT<<<dim3(12, 64, 16), 256, 0, stream>>>(c3, c4, fusedT);
    gemm_bn_relu<<<dim3(32, 4, 16), 256, 0, stream>>>(wbf, fusedT, scale, shift, attr);
    build_P<<<dim3(160, 25), 256, 0, stream>>>(boxes, P);
    pool_gemm<<<dim3(2, 16, 16), 256, 0, stream>>>(P, attr, part2);
    pool_reduce<<<(BATCH * MPAD * COUT) / 256, 256, 0, stream>>>(part2, out);
    (void)in_sizes; (void)n_in; (void)out_size; (void)ws_size;
}

// Round 9
// 460.855 us; speedup vs baseline: 1.5899x; 1.1870x over previous
//
#include <hip/hip_runtime.h>
#include <stdint.h>

#define FH 64
#define FW 64
#define CIN 1536
#define C3C 512
#define C4C 1024
#define COUT 512
#define BATCH 16
#define NPIX 4096
#define NBOX 10
#define MPAD 256   // 10 boxes * 25 bins = 250, padded

typedef float v4f __attribute__((ext_vector_type(4)));

#define GLOAD_LDS16(g, l) __builtin_amdgcn_global_load_lds( \
    (const __attribute__((address_space(1))) void*)(g),     \
    (__attribute__((address_space(3))) void*)(l), 16, 0, 0)

// pack 4 floats -> 4 fp8 e4m3 bytes in one u32 (byte k = f[k])
__device__ __forceinline__ uint32_t pack4_fp8(float a, float b, float c, float d) {
    int lo = __builtin_amdgcn_cvt_pk_fp8_f32(a, b, 0, false);
    int v  = __builtin_amdgcn_cvt_pk_fp8_f32(c, d, lo, true);
    return (uint32_t)v;
}
__device__ __forceinline__ unsigned char f32_to_fp8(float a) {
    return (unsigned char)(__builtin_amdgcn_cvt_pk_fp8_f32(a, a, 0, false) & 0xff);
}

// ---------------- BN constant folding (W was scaled x16 -> scale/16) -------
__global__ void prep_bn(const float* __restrict__ bng, const float* __restrict__ bnb,
                        const float* __restrict__ bnm, const float* __restrict__ bnv,
                        const float* __restrict__ bconv,
                        float* __restrict__ scale, float* __restrict__ shift) {
    int o = threadIdx.x;
    if (o < COUT) {
        float inv = bng[o] / sqrtf(bnv[o] + 1e-5f);
        scale[o] = inv * 0.0625f;             // /16: W quantized as W*16
        shift[o] = bnb[o] + inv * (bconv[o] - bnm[o]);
    }
}

// ---------------- W f32 -> fp8 (x16) ---------------------------------------
__global__ void conv_w(const float* __restrict__ w, uint32_t* __restrict__ w8, int n4) {
    int i = blockIdx.x * 256 + threadIdx.x;
    if (i < n4) {
        float4 f = *(const float4*)(w + i * 4);
        w8[i] = pack4_fp8(f.x * 16.0f, f.y * 16.0f, f.z * 16.0f, f.w * 16.0f);
    }
}

// ---------------- build fusedT[b][pix][c] fp8 (K-major) --------------------
// tile: 128 channels x 64 px (one y row). LDS u32 = 4 packed channels.
__global__ __launch_bounds__(256) void build_fusedT(const float* __restrict__ c3,
                                                    const float* __restrict__ c4,
                                                    unsigned char* __restrict__ fusedT) {
    __shared__ uint32_t lds[64 * 36];
    int ct = blockIdx.x;          // 0..11; <4 -> c3, else c4
    int y  = blockIdx.y;
    int b  = blockIdx.z;
    int t  = threadIdx.x;
    int pg = t & 15;              // pixel quad: px 4pg..4pg+3
    int cq = t >> 4;              // 0..15; cquad = cq + 16r

    #pragma unroll
    for (int r = 0; r < 2; ++r) {
        int cquad = cq + 16 * r;
        float vv[4][4];           // [channel][pixel]
        if (ct < 4) {
            int ch = ct * 128 + 4 * cquad;
            const float* src = c3 + (((size_t)(b * C3C + ch) * FH + y) * FW) + 4 * pg;
            #pragma unroll
            for (int k = 0; k < 4; ++k) {
                float4 f = *(const float4*)(src + (size_t)k * (FH * FW));
                vv[k][0] = f.x; vv[k][1] = f.y; vv[k][2] = f.z; vv[k][3] = f.w;
            }
        } else {
            int ch = ct * 128 - 512 + 4 * cquad;
            int jy = y >> 1;
            int jyB = min(max(jy + ((y & 1) ? 1 : -1), 0), 31);
            int k0 = 2 * pg;
            int km = max(k0 - 1, 0), kp = min(k0 + 2, 31);
            const float* base = c4 + (size_t)(b * C4C + ch) * 1024;
            #pragma unroll
            for (int k = 0; k < 4; ++k) {
                const float* pc = base + (size_t)k * 1024;
                const float* r0 = pc + jy * 32;
                const float* r1 = pc + jyB * 32;
                float rbm = 0.75f * r0[km]     + 0.25f * r1[km];
                float rb0 = 0.75f * r0[k0]     + 0.25f * r1[k0];
                float rb1 = 0.75f * r0[k0 + 1] + 0.25f * r1[k0 + 1];
                float rbp = 0.75f * r0[kp]     + 0.25f * r1[kp];
                vv[k][0] = 0.75f * rb0 + 0.25f * rbm;
                vv[k][1] = 0.75f * rb0 + 0.25f * rb1;
                vv[k][2] = 0.75f * rb1 + 0.25f * rb0;
                vv[k][3] = 0.75f * rb1 + 0.25f * rbp;
            }
        }
        #pragma unroll
        for (int i = 0; i < 4; ++i)
            lds[(4 * pg + i) * 36 + cquad] = pack4_fp8(vv[0][i], vv[1][i], vv[2][i], vv[3][i]);
    }
    __syncthreads();
    // write: 64 px x 128 B; thread covers 2 x 16 B
    int g = t & 7;                 // 16-channel group
    #pragma unroll
    for (int rr = 0; rr < 2; ++rr) {
        int px = (t >> 3) + 32 * rr;
        uint4 w = *(const uint4*)(&lds[px * 36 + 4 * g]);
        *(uint4*)(fusedT + ((size_t)b * NPIX + y * FW + px) * CIN + ct * 128 + g * 16) = w;
    }
}

// ---------------- fp8 GEMM + BN + ReLU, BK=64, channel-major fp8 out -------
__global__ __launch_bounds__(256) void gemm_bn_relu(
        const unsigned char* __restrict__ w8,
        const unsigned char* __restrict__ fusedT,
        const float* __restrict__ scale, const float* __restrict__ shift,
        unsigned char* __restrict__ attr) {
    __shared__ __align__(16) unsigned char lds_a[128 * 64];
    __shared__ __align__(16) unsigned char lds_b[128 * 64];
    int t  = threadIdx.x;
    int n0 = blockIdx.x * 128;   // pixel tile
    int o0 = blockIdx.y * 128;   // out-channel tile
    int b  = blockIdx.z;
    int wave = t >> 6, lane = t & 63;
    int wm = wave & 1, wn = wave >> 1;
    int quad = lane >> 4, l16 = lane & 15;
    const unsigned char* fb = fusedT + (size_t)b * NPIX * CIN;

    v4f acc[4][4];
    #pragma unroll
    for (int i = 0; i < 4; ++i)
        #pragma unroll
        for (int j = 0; j < 4; ++j) acc[i][j] = (v4f)0.0f;

    // staging: row = t>>2 (and +64), 16-B chunk (t&3) XOR-swizzled by row&3
    int row = t >> 2;
    int cg  = (t & 3) ^ (row & 3);
    const unsigned char* ga0 = w8 + (size_t)(o0 + row) * CIN + cg * 16;
    const unsigned char* ga1 = w8 + (size_t)(o0 + row + 64) * CIN + cg * 16;
    const unsigned char* gb0 = fb + (size_t)(n0 + row) * CIN + cg * 16;
    const unsigned char* gb1 = fb + (size_t)(n0 + row + 64) * CIN + cg * 16;
    unsigned char* la0 = lds_a + t * 16;
    unsigned char* la1 = lds_a + 4096 + t * 16;
    unsigned char* lb0 = lds_b + t * 16;
    unsigned char* lb1 = lds_b + 4096 + t * 16;

    int ra[4], rb[4];
    #pragma unroll
    for (int i = 0; i < 4; ++i) { ra[i] = wm * 64 + i * 16 + l16; rb[i] = wn * 64 + i * 16 + l16; }
    int q2 = quad >> 1, q1 = (quad & 1) * 8;

    for (int kt = 0; kt < CIN / 64; ++kt) {
        __syncthreads();
        GLOAD_LDS16(ga0, la0);
        GLOAD_LDS16(ga1, la1);
        GLOAD_LDS16(gb0, lb0);
        GLOAD_LDS16(gb1, lb1);
        ga0 += 64; ga1 += 64; gb0 += 64; gb1 += 64;
        __syncthreads();

        #pragma unroll
        for (int s = 0; s < 2; ++s) {
            long af[4], bf[4];
            #pragma unroll
            for (int i = 0; i < 4; ++i) {
                int pa = (2 * s + q2) ^ (ra[i] & 3);
                af[i] = *(const long*)(lds_a + ra[i] * 64 + pa * 16 + q1);
                int pb = (2 * s + q2) ^ (rb[i] & 3);
                bf[i] = *(const long*)(lds_b + rb[i] * 64 + pb * 16 + q1);
            }
            #pragma unroll
            for (int i = 0; i < 4; ++i)
                #pragma unroll
                for (int j = 0; j < 4; ++j)
                    acc[i][j] = __builtin_amdgcn_mfma_f32_16x16x32_fp8_fp8(af[i], bf[j], acc[i][j], 0, 0, 0);
        }
    }

    unsigned char* ab = attr + (size_t)b * COUT * NPIX;
    #pragma unroll
    for (int i = 0; i < 4; ++i) {
        int obase = o0 + wm * 64 + i * 16 + quad * 4;
        #pragma unroll
        for (int r = 0; r < 4; ++r) {
            int oo = obase + r;
            float sc = scale[oo], sh = shift[oo];
            #pragma unroll
            for (int j = 0; j < 4; ++j) {
                int n = n0 + wn * 64 + j * 16 + l16;
                float v = fmaxf(acc[i][j][r] * sc + sh, 0.0f);
                ab[(size_t)oo * NPIX + n] = f32_to_fp8(v);
            }
        }
    }
}

// ---------------- build pooling matrix P[b][m][pix] fp8 (x64) --------------
__global__ __launch_bounds__(256) void build_P(const float* __restrict__ boxes,
                                               unsigned char* __restrict__ P) {
    int br  = blockIdx.x;                // 0..159
    int m25 = blockIdx.y;                // 0..24
    int b   = br / NBOX;
    int m   = (br % NBOX) * 25 + m25;
    int p   = m25 / 5, q = m25 % 5;
    int t   = threadIdx.x;
    int y   = t >> 2;
    int x0  = (t & 3) * 16;
    const float* bx = boxes + (size_t)br * 4;
    int x1 = min(max((int)floorf(bx[0] * 0.125f), 0), 63);
    int y1 = min(max((int)floorf(bx[1] * 0.125f), 0), 63);
    int x2 = min(max((int)ceilf (bx[2] * 0.125f), 0), 63);
    int y2 = min(max((int)ceilf (bx[3] * 0.125f), 0), 63);
    if (x2 <= x1) x2 = min(x1 + 1, 64);
    if (y2 <= y1) y2 = min(y1 + 1, 64);
    int Lx = x2 - x1, Ly = y2 - y1;
    int sx = x1 + (q * Lx) / 5;
    int ex = x1 + ((q + 1) * Lx + 4) / 5;
    int sy = y1 + (p * Ly) / 5;
    int ey = y1 + ((p + 1) * Ly + 4) / 5;
    float wyv  = (y >= sy && y < ey) ? 1.0f / (float)(ey - sy) : 0.0f;
    float pval = 64.0f * wyv / (float)(ex - sx);
    float v[16];
    #pragma unroll
    for (int i = 0; i < 16; ++i) {
        int xi = x0 + i;
        v[i] = (xi >= sx && xi < ex) ? pval : 0.0f;
    }
    uint4 w;
    w.x = pack4_fp8(v[0],  v[1],  v[2],  v[3]);
    w.y = pack4_fp8(v[4],  v[5],  v[6],  v[7]);
    w.z = pack4_fp8(v[8],  v[9],  v[10], v[11]);
    w.w = pack4_fp8(v[12], v[13], v[14], v[15]);
    *(uint4*)(P + ((size_t)b * MPAD + m) * NPIX + y * FW + x0) = w;
}

// ---------------- fp8 pool GEMM, K-split x4, dense partials ----------------
__global__ __launch_bounds__(256) void pool_gemm(
        const unsigned char* __restrict__ P,
        const unsigned char* __restrict__ attr,
        float* __restrict__ part2) {
    __shared__ __align__(16) unsigned char lds_a[128 * 64];
    __shared__ __align__(16) unsigned char lds_b[128 * 64];
    int t  = threadIdx.x;
    int m0 = blockIdx.x * 128;
    int c0 = (blockIdx.y & 3) * 128;
    int seg = blockIdx.y >> 2;
    int b  = blockIdx.z;
    int wave = t >> 6, lane = t & 63;
    int wm = wave & 1, wn = wave >> 1;
    int quad = lane >> 4, l16 = lane & 15;
    const unsigned char* Pb = P + (size_t)b * MPAD * NPIX + seg * 1024;
    const unsigned char* ab = attr + (size_t)b * COUT * NPIX + seg * 1024;

    v4f acc[4][4];
    #pragma unroll
    for (int i = 0; i < 4; ++i)
        #pragma unroll
        for (int j = 0; j < 4; ++j) acc[i][j] = (v4f)0.0f;

    int row = t >> 2;
    int cg  = (t & 3) ^ (row & 3);
    const unsigned char* ga0 = Pb + (size_t)(m0 + row) * NPIX + cg * 16;
    const unsigned char* ga1 = Pb + (size_t)(m0 + row + 64) * NPIX + cg * 16;
    const unsigned char* gb0 = ab + (size_t)(c0 + row) * NPIX + cg * 16;
    const unsigned char* gb1 = ab + (size_t)(c0 + row + 64) * NPIX + cg * 16;
    unsigned char* la0 = lds_a + t * 16;
    unsigned char* la1 = lds_a + 4096 + t * 16;
    unsigned char* lb0 = lds_b + t * 16;
    unsigned char* lb1 = lds_b + 4096 + t * 16;

    int ra[4], rb[4];
    #pragma unroll
    for (int i = 0; i < 4; ++i) { ra[i] = wm * 64 + i * 16 + l16; rb[i] = wn * 64 + i * 16 + l16; }
    int q2 = quad >> 1, q1 = (quad & 1) * 8;

    for (int kt = 0; kt < 1024 / 64; ++kt) {
        __syncthreads();
        GLOAD_LDS16(ga0, la0);
        GLOAD_LDS16(ga1, la1);
        GLOAD_LDS16(gb0, lb0);
        GLOAD_LDS16(gb1, lb1);
        ga0 += 64; ga1 += 64; gb0 += 64; gb1 += 64;
        __syncthreads();

        #pragma unroll
        for (int s = 0; s < 2; ++s) {
            long af[4], bf[4];
            #pragma unroll
            for (int i = 0; i < 4; ++i) {
                int pa = (2 * s + q2) ^ (ra[i] & 3);
                af[i] = *(const long*)(lds_a + ra[i] * 64 + pa * 16 + q1);
                int pb = (2 * s + q2) ^ (rb[i] & 3);
                bf[i] = *(const long*)(lds_b + rb[i] * 64 + pb * 16 + q1);
            }
            #pragma unroll
            for (int i = 0; i < 4; ++i)
                #pragma unroll
                for (int j = 0; j < 4; ++j)
                    acc[i][j] = __builtin_amdgcn_mfma_f32_16x16x32_fp8_fp8(af[i], bf[j], acc[i][j], 0, 0, 0);
        }
    }

    float* pp = part2 + (((size_t)seg * BATCH + b) * MPAD) * COUT;
    #pragma unroll
    for (int i = 0; i < 4; ++i) {
        #pragma unroll
        for (int r = 0; r < 4; ++r) {
            int mrow = m0 + wm * 64 + i * 16 + quad * 4 + r;
            #pragma unroll
            for (int j = 0; j < 4; ++j) {
                int c = c0 + wn * 64 + j * 16 + l16;
                pp[(size_t)mrow * COUT + c] = acc[i][j][r];
            }
        }
    }
}

// ---------------- reduce 4 segs (/64 for P scaling), transpose to out ------
__global__ __launch_bounds__(256) void pool_reduce(const float* __restrict__ part2,
                                                   float* __restrict__ out) {
    const size_t SEG = (size_t)BATCH * MPAD * COUT;
    int i = blockIdx.x * 256 + threadIdx.x;
    int c = i & (COUT - 1);
    int m = (i >> 9) & (MPAD - 1);
    int b = i >> 17;
    if (m >= 250) return;
    float s = part2[i] + part2[i + SEG] + part2[i + 2 * SEG] + part2[i + 3 * SEG];
    int box = m / 25, bin = m - box * 25;
    out[640 + ((size_t)(b * NBOX + box) * COUT + c) * 25 + bin] = s * 0.015625f;
}

extern "C" void kernel_launch(void* const* d_in, const int* in_sizes, int n_in,
                              void* d_out, int out_size, void* d_ws, size_t ws_size,
                              hipStream_t stream) {
    const float* c3     = (const float*)d_in[0];
    const float* c4     = (const float*)d_in[1];
    const float* boxes  = (const float*)d_in[2];
    const float* w_conv = (const float*)d_in[3];
    const float* b_conv = (const float*)d_in[4];
    const float* bng    = (const float*)d_in[5];
    const float* bnb    = (const float*)d_in[6];
    const float* bnm    = (const float*)d_in[7];
    const float* bnv    = (const float*)d_in[8];
    float* out = (float*)d_out;

    char* ws = (char*)d_ws;
    // fp8 layout (no aliasing needed):
    unsigned char* fusedT = (unsigned char*)ws;                 // 100663296 B
    unsigned char* P      = (unsigned char*)(ws + 100663296);   //  16777216 B
    float*         part2  = (float*)(ws + 117440512);           //  33554432 B
    unsigned char* w8     = (unsigned char*)(ws + 150994944);   //    786432 B
    float*         scale  = (float*)(ws + 151781376);           //      2048 B
    float*         shift  = (float*)(ws + 151783424);           //      2048 B
    unsigned char* attr   = (unsigned char*)(ws + 151785472);   //  33554432 B

    hipMemcpyAsync(d_out, d_in[2], 640 * sizeof(float), hipMemcpyDeviceToDevice, stream);
    prep_bn<<<1, 512, 0, stream>>>(bng, bnb, bnm, bnv, b_conv, scale, shift);
    conv_w<<<(COUT * CIN / 4 + 255) / 256, 256, 0, stream>>>(w_conv, (uint32_t*)w8, COUT * CIN / 4);
    build_P<<<dim3(160, 25), 256, 0, stream>>>(boxes, P);
    build_fusedT<<<dim3(12, 64, 16), 256, 0, stream>>>(c3, c4, fusedT);
    gemm_bn_relu<<<dim3(32, 4, 16), 256, 0, stream>>>(w8, fusedT, scale, shift, attr);
    pool_gemm<<<dim3(2, 16, 16), 256, 0, stream>>>(P, attr, part2);
    pool_reduce<<<(BATCH * MPAD * COUT) / 256, 256, 0, stream>>>(part2, out);
    (void)in_sizes; (void)n_in; (void)out_size; (void)ws_size;
}